// Round 1
// baseline (9157.430 us; speedup 1.0000x reference)
//
#include <hip/hip_runtime.h>
#include <hip/hip_bf16.h>

typedef __attribute__((ext_vector_type(8))) short short8;
typedef __attribute__((ext_vector_type(4))) float f32x4;

// Problem dims
#define NB 64      // batch
#define NS 1024    // seq
#define ND 512     // input dim
#define NH 512     // hidden
#define NG 2048    // 4*NH gate columns
#define M1 65536   // NB*NS rows of the input-projection GEMM

// ws layout (bytes)
#define OFF_A    0L                      // A bf16 [65536][512]           64 MB
#define OFF_XG   67108864L               // xg bf16 [1024][64][2048]     256 MB
#define OFF_WXT  335544320L              // Wxt bf16 [2048][512]           2 MB
#define OFF_WHT  337641472L              // Wht bf16 [2048][512]           2 MB
#define OFF_BC   339738624L              // bcat f32 [2048]                8 KB
#define OFF_HB   339746816L              // hbuf bf16 [2][64][512]       128 KB
#define OFF_BAR  339877888L              // barrier counter u32

#define OUT_HF   33554432L               // d_out offset of h_final
#define OUT_CF   33587200L               // d_out offset of c_final

static __device__ __forceinline__ ushort f2bf(float x) {
  union { float f; unsigned u; } v; v.f = x;
  unsigned r = (v.u + 0x7FFFu + ((v.u >> 16) & 1u)) >> 16;
  return (ushort)r;
}
static __device__ __forceinline__ float bf2f(ushort x) {
  union { unsigned u; float f; } v; v.u = ((unsigned)x) << 16; return v.f;
}
static __device__ __forceinline__ float sigm(float x) {
  return 1.0f / (1.0f + __expf(-x));
}
static __device__ __forceinline__ float tanh_fast(float x) {
  // 2*sigmoid(2x)-1 : no overflow (exp(-2x) saturates to inf -> -1, to 0 -> +1)
  return 2.0f / (1.0f + __expf(-2.0f * x)) - 1.0f;
}

// ---------- phase 0a: fp32 -> bf16 convert of inputs ----------
__global__ __launch_bounds__(256) void cvt_in_k(const float* __restrict__ in,
                                                ushort* __restrict__ out) {
  long i = ((long)blockIdx.x * 256 + threadIdx.x) * 8;
  const float4* p = (const float4*)(in + i);
  float4 a = p[0], b = p[1];
  short8 o;
  o[0] = (short)f2bf(a.x); o[1] = (short)f2bf(a.y);
  o[2] = (short)f2bf(a.z); o[3] = (short)f2bf(a.w);
  o[4] = (short)f2bf(b.x); o[5] = (short)f2bf(b.y);
  o[6] = (short)f2bf(b.z); o[7] = (short)f2bf(b.w);
  *(short8*)(out + i) = o;
}

// ---------- phase 0b: transpose+convert weights, pack biases ----------
// Wxt[n][k] = Wx_gate[k][col], n = gate*512+col (n-major, k contiguous)
__global__ __launch_bounds__(256) void prep_w_k(
    const float* __restrict__ Wxi, const float* __restrict__ Whi, const float* __restrict__ bi,
    const float* __restrict__ Wxf, const float* __restrict__ Whf, const float* __restrict__ bff,
    const float* __restrict__ Wxo, const float* __restrict__ Who, const float* __restrict__ bo,
    const float* __restrict__ Wxc, const float* __restrict__ Whc, const float* __restrict__ bc,
    ushort* __restrict__ Wxt, ushort* __restrict__ Wht, float* __restrict__ bcat) {
  int t = blockIdx.x * 256 + threadIdx.x;   // 0 .. 2048*512-1
  int n = t >> 9, k = t & 511;
  int g = n >> 9, col = n & 511;
  const float* wx = (g == 0) ? Wxi : (g == 1) ? Wxf : (g == 2) ? Wxo : Wxc;
  const float* wh = (g == 0) ? Whi : (g == 1) ? Whf : (g == 2) ? Who : Whc;
  Wxt[t] = f2bf(wx[k * 512 + col]);
  Wht[t] = f2bf(wh[k * 512 + col]);
  if (t < 2048) {
    int g2 = t >> 9;
    const float* bp = (g2 == 0) ? bi : (g2 == 1) ? bff : (g2 == 2) ? bo : bc;
    bcat[t] = bp[t & 511];
  }
}

// ---------- phase 1: xg = A @ Wxt^T + b  (bf16 MFMA, 128x128 tiles, BK=32) ----------
// A: [65536][512] bf16 row-major. Wxt: [2048 n][512 k] bf16 (B already n-major).
// Output xg time-major: xg[(s*64+b)*2048 + n] bf16.
__global__ __launch_bounds__(256) void gemm_x_k(const ushort* __restrict__ A,
                                                const ushort* __restrict__ Bt,
                                                const float* __restrict__ bcat,
                                                ushort* __restrict__ xg) {
  __shared__ ushort As[128 * 40];  // +8 bf16 pad -> 80B row stride (2-way banks, free)
  __shared__ ushort Bs[128 * 40];
  const int mbase = blockIdx.x * 128;
  const int nbase = blockIdx.y * 128;
  const int tid = threadIdx.x;
  const int lane = tid & 63, wave = tid >> 6;
  const int l15 = lane & 15, q = lane >> 4;
  const int wm = (wave & 1) * 64, wn = (wave >> 1) * 64;

  f32x4 acc[4][4];
#pragma unroll
  for (int j = 0; j < 4; ++j) {
    float bv = bcat[nbase + wn + j * 16 + l15];
#pragma unroll
    for (int i = 0; i < 4; ++i) acc[i][j] = (f32x4){bv, bv, bv, bv};
  }

  const int sr = tid >> 2;           // staging row (0..63), two passes
  const int skk = (tid & 3) * 8;     // staging k offset (elems)

  for (int kt = 0; kt < 16; ++kt) {
    const int kb = kt * 32;
#pragma unroll
    for (int pass = 0; pass < 2; ++pass) {
      int rr = sr + pass * 64;
      *(short8*)&As[rr * 40 + skk] = *(const short8*)&A[(long)(mbase + rr) * 512 + kb + skk];
      *(short8*)&Bs[rr * 40 + skk] = *(const short8*)&Bt[(long)(nbase + rr) * 512 + kb + skk];
    }
    __syncthreads();
    short8 af[4], bfr[4];
#pragma unroll
    for (int i = 0; i < 4; ++i)
      af[i] = *(const short8*)&As[(wm + i * 16 + l15) * 40 + q * 8];
#pragma unroll
    for (int j = 0; j < 4; ++j)
      bfr[j] = *(const short8*)&Bs[(wn + j * 16 + l15) * 40 + q * 8];
#pragma unroll
    for (int i = 0; i < 4; ++i)
#pragma unroll
      for (int j = 0; j < 4; ++j)
        acc[i][j] = __builtin_amdgcn_mfma_f32_16x16x32_bf16(af[i], bfr[j], acc[i][j], 0, 0, 0);
    __syncthreads();
  }

  // epilogue: C row m -> (b = m>>10, s = m&1023); write xg[(s*64+b)*2048 + n] bf16
#pragma unroll
  for (int i = 0; i < 4; ++i) {
#pragma unroll
    for (int r = 0; r < 4; ++r) {
      int m = mbase + wm + i * 16 + q * 4 + r;
      int b = m >> 10, s = m & 1023;
      long rowoff = ((long)(s * 64 + b)) * 2048;
#pragma unroll
      for (int j = 0; j < 4; ++j) {
        int n = nbase + wn + j * 16 + l15;
        xg[rowoff + n] = f2bf(acc[i][j][r]);
      }
    }
  }
}

// ---------- device-scope barrier (monotonic counter, 64 WGs) ----------
static __device__ __forceinline__ void gridbar(unsigned* bar, unsigned k) {
  __syncthreads();                 // all WG stores program-complete (vmcnt drained)
  if (threadIdx.x == 0) {
    __threadfence();               // agent release: L2 writeback (cross-XCD publish)
    atomicAdd(bar, 1u);
    const unsigned target = 64u * k;
    while (__hip_atomic_load(bar, __ATOMIC_RELAXED, __HIP_MEMORY_SCOPE_AGENT) < target) {
      __builtin_amdgcn_s_sleep(2);
    }
    __threadfence();               // agent acquire: L1/L2 invalidate
  }
  __syncthreads();
}

// ---------- phase 2: persistent recurrence, 64 WGs, column-split ----------
// WG j owns h-cols [j*8, j*8+8). Local gate-col n in [0,32): gate = n>>3, c = n&7.
// Wave w = m-tile (batch rows w*16..w*16+15). Wh slice register-resident.
__global__ __launch_bounds__(256, 1) void lstm_rec_k(const ushort* __restrict__ xg,
                                                     const ushort* __restrict__ Wht,
                                                     float* __restrict__ out,
                                                     ushort* hbuf, unsigned* bar) {
  const int j = blockIdx.x;        // 0..63
  const int tid = threadIdx.x;
  const int wave = tid >> 6, lane = tid & 63;
  const int l15 = lane & 15, q = lane >> 4;

  // B fragments: bfrag[ntile p][ktile] ; B[k][n]: n = lane&15, k = kt*32 + q*8 + 0..7
  short8 bfrag[2][16];
#pragma unroll
  for (int p = 0; p < 2; ++p) {
    int nloc = p * 16 + l15;
    int gate = nloc >> 3;
    long ng = gate * 512 + j * 8 + (nloc & 7);
#pragma unroll
    for (int kt = 0; kt < 16; ++kt)
      bfrag[p][kt] = *(const short8*)&Wht[ng * 512 + kt * 32 + q * 8];
  }

  // zero h_0 slice (buf 0, cols j*8..+8, all 64 rows)
  for (int e = tid; e < 512; e += 256) {
    int r = e >> 3, c = e & 7;
    hbuf[r * 512 + j * 8 + c] = 0;
  }

  float c4[4] = {0.f, 0.f, 0.f, 0.f};
  const int row0 = wave * 16 + q * 4;       // C-layout rows this lane owns
  const int hcol = j * 8 + (lane & 7);
  const bool wr = (lane & 8) == 0;          // lane-pair deduplication for stores
  // xg column index per ntile (fixed over t)
  int gcol[2];
#pragma unroll
  for (int p = 0; p < 2; ++p) {
    int nloc = p * 16 + l15;
    gcol[p] = (nloc >> 3) * 512 + j * 8 + (nloc & 7);
  }
  const int arow = wave * 16 + l15;         // A-fragment row

  gridbar(bar, 1);                          // publish h_0

  for (int t = 0; t < 1024; ++t) {
    const ushort* hsrc = hbuf + (t & 1) * (64 * 512);

    // A fragments straight from global (h is L2/L3-resident, 16B/lane loads)
    short8 af[16];
#pragma unroll
    for (int kt = 0; kt < 16; ++kt)
      af[kt] = *(const short8*)&hsrc[arow * 512 + kt * 32 + q * 8];

    // acc init = x-projection (bf16) for this lane's C elements
    f32x4 acc[2];
    long xbase = ((long)t * 64) * 2048;
#pragma unroll
    for (int p = 0; p < 2; ++p)
#pragma unroll
      for (int r = 0; r < 4; ++r)
        acc[p][r] = bf2f(xg[xbase + (long)(row0 + r) * 2048 + gcol[p]]);

#pragma unroll
    for (int kt = 0; kt < 16; ++kt) {
      acc[0] = __builtin_amdgcn_mfma_f32_16x16x32_bf16(af[kt], bfrag[0][kt], acc[0], 0, 0, 0);
      acc[1] = __builtin_amdgcn_mfma_f32_16x16x32_bf16(af[kt], bfrag[1][kt], acc[1], 0, 0, 0);
    }

    // elementwise: lane (bit3=0) has gates i (acc0) and o (acc1); partner lane^8 has f, g
    const int wt = (t + 1) & 1;
#pragma unroll
    for (int r = 0; r < 4; ++r) {
      float a0 = acc[0][r], a1 = acc[1][r];
      float o0 = __shfl_xor(a0, 8);
      float o1 = __shfl_xor(a1, 8);
      float pi = wr ? a0 : o0;
      float pf = wr ? o0 : a0;
      float po = wr ? a1 : o1;
      float pg = wr ? o1 : a1;
      float ig = sigm(pi), fg = sigm(pf), og = sigm(po), gg = tanh_fast(pg);
      float cc = fg * c4[r] + ig * gg;
      c4[r] = cc;
      float hn = og * tanh_fast(cc);
      if (wr) {
        int m = row0 + r;  // batch index
        hbuf[wt * (64 * 512) + m * 512 + hcol] = f2bf(hn);
        out[(long)m * (NS * NH) + (long)t * NH + hcol] = hn;
        if (t == 1023) {
          out[OUT_HF + m * 512 + hcol] = hn;
          out[OUT_CF + m * 512 + hcol] = cc;
        }
      }
    }
    if (t < 1023) gridbar(bar, (unsigned)(t + 2));
  }
}

extern "C" void kernel_launch(void* const* d_in, const int* in_sizes, int n_in,
                              void* d_out, int out_size, void* d_ws, size_t ws_size,
                              hipStream_t stream) {
  const float* inputs = (const float*)d_in[0];
  const float* Wxi = (const float*)d_in[1];
  const float* Whi = (const float*)d_in[2];
  const float* bi  = (const float*)d_in[3];
  const float* Wxf = (const float*)d_in[4];
  const float* Whf = (const float*)d_in[5];
  const float* bff = (const float*)d_in[6];
  const float* Wxo = (const float*)d_in[7];
  const float* Who = (const float*)d_in[8];
  const float* bo  = (const float*)d_in[9];
  const float* Wxc = (const float*)d_in[10];
  const float* Whc = (const float*)d_in[11];
  const float* bc  = (const float*)d_in[12];

  char* ws = (char*)d_ws;
  ushort*  Abf  = (ushort*)(ws + OFF_A);
  ushort*  xgp  = (ushort*)(ws + OFF_XG);
  ushort*  Wxt  = (ushort*)(ws + OFF_WXT);
  ushort*  Whtp = (ushort*)(ws + OFF_WHT);
  float*   bcat = (float*)(ws + OFF_BC);
  ushort*  hbuf = (ushort*)(ws + OFF_HB);
  unsigned* bar = (unsigned*)(ws + OFF_BAR);

  hipMemsetAsync(bar, 0, sizeof(unsigned), stream);

  cvt_in_k<<<16384, 256, 0, stream>>>(inputs, Abf);                 // 33.5M elems
  prep_w_k<<<4096, 256, 0, stream>>>(Wxi, Whi, bi, Wxf, Whf, bff,
                                     Wxo, Who, bo, Wxc, Whc, bc,
                                     Wxt, Whtp, bcat);
  dim3 g1(M1 / 128, NG / 128);                                      // 512 x 16
  gemm_x_k<<<g1, 256, 0, stream>>>(Abf, Wxt, bcat, xgp);
  // 64 persistent WGs on 256 CUs: trivially co-resident for the spin barrier
  lstm_rec_k<<<64, 256, 0, stream>>>(xgp, Whtp, (float*)d_out, hbuf, bar);
}

// Round 2
// 7054.402 us; speedup vs baseline: 1.2981x; 1.2981x over previous
//
#include <hip/hip_runtime.h>
#include <hip/hip_bf16.h>

typedef __attribute__((ext_vector_type(8))) short short8;
typedef __attribute__((ext_vector_type(4))) float f32x4;

// Problem dims
#define NB 64      // batch
#define NS 1024    // seq
#define ND 512     // input dim
#define NH 512     // hidden
#define NG 2048    // 4*NH gate columns
#define M1 65536   // NB*NS rows of the input-projection GEMM

// ws layout (bytes)
#define OFF_A    0L                      // A bf16 [65536][512]           64 MB
#define OFF_XG   67108864L               // xg bf16 [1024][64][2048]     256 MB
#define OFF_WXT  335544320L              // Wxt bf16 [2048][512]           2 MB
#define OFF_WHT  337641472L              // Wht bf16 [2048][512]           2 MB
#define OFF_BC   339738624L              // bcat f32 [2048]                8 KB
#define OFF_HB   339746816L              // hb u32 [2][64][256]          128 KB (bf16 pairs)
#define OFF_BAR  339877888L              // flags u32[64]

#define OUT_HF   33554432L               // d_out offset of h_final
#define OUT_CF   33587200L               // d_out offset of c_final

static __device__ __forceinline__ ushort f2bf(float x) {
  union { float f; unsigned u; } v; v.f = x;
  unsigned r = (v.u + 0x7FFFu + ((v.u >> 16) & 1u)) >> 16;
  return (ushort)r;
}
static __device__ __forceinline__ float bf2f(ushort x) {
  union { unsigned u; float f; } v; v.u = ((unsigned)x) << 16; return v.f;
}
static __device__ __forceinline__ float sigm(float x) {
  return 1.0f / (1.0f + __expf(-x));
}
static __device__ __forceinline__ float tanh_fast(float x) {
  return 2.0f / (1.0f + __expf(-2.0f * x)) - 1.0f;
}

// ---------- phase 0a: fp32 -> bf16 convert of inputs ----------
__global__ __launch_bounds__(256) void cvt_in_k(const float* __restrict__ in,
                                                ushort* __restrict__ out) {
  long i = ((long)blockIdx.x * 256 + threadIdx.x) * 8;
  const float4* p = (const float4*)(in + i);
  float4 a = p[0], b = p[1];
  short8 o;
  o[0] = (short)f2bf(a.x); o[1] = (short)f2bf(a.y);
  o[2] = (short)f2bf(a.z); o[3] = (short)f2bf(a.w);
  o[4] = (short)f2bf(b.x); o[5] = (short)f2bf(b.y);
  o[6] = (short)f2bf(b.z); o[7] = (short)f2bf(b.w);
  *(short8*)(out + i) = o;
}

// ---------- phase 0b: transpose+convert weights, pack biases ----------
__global__ __launch_bounds__(256) void prep_w_k(
    const float* __restrict__ Wxi, const float* __restrict__ Whi, const float* __restrict__ bi,
    const float* __restrict__ Wxf, const float* __restrict__ Whf, const float* __restrict__ bff,
    const float* __restrict__ Wxo, const float* __restrict__ Who, const float* __restrict__ bo,
    const float* __restrict__ Wxc, const float* __restrict__ Whc, const float* __restrict__ bc,
    ushort* __restrict__ Wxt, ushort* __restrict__ Wht, float* __restrict__ bcat) {
  int t = blockIdx.x * 256 + threadIdx.x;   // 0 .. 2048*512-1
  int n = t >> 9, k = t & 511;
  int g = n >> 9, col = n & 511;
  const float* wx = (g == 0) ? Wxi : (g == 1) ? Wxf : (g == 2) ? Wxo : Wxc;
  const float* wh = (g == 0) ? Whi : (g == 1) ? Whf : (g == 2) ? Who : Whc;
  Wxt[t] = f2bf(wx[k * 512 + col]);
  Wht[t] = f2bf(wh[k * 512 + col]);
  if (t < 2048) {
    int g2 = t >> 9;
    const float* bp = (g2 == 0) ? bi : (g2 == 1) ? bff : (g2 == 2) ? bo : bc;
    bcat[t] = bp[t & 511];
  }
}

// ---------- phase 1: xg = A @ Wxt^T + b  (bf16 MFMA, 128x128 tiles, BK=32) ----------
__global__ __launch_bounds__(256) void gemm_x_k(const ushort* __restrict__ A,
                                                const ushort* __restrict__ Bt,
                                                const float* __restrict__ bcat,
                                                ushort* __restrict__ xg) {
  __shared__ ushort As[128 * 40];
  __shared__ ushort Bs[128 * 40];
  const int mbase = blockIdx.x * 128;
  const int nbase = blockIdx.y * 128;
  const int tid = threadIdx.x;
  const int lane = tid & 63, wave = tid >> 6;
  const int l15 = lane & 15, q = lane >> 4;
  const int wm = (wave & 1) * 64, wn = (wave >> 1) * 64;

  f32x4 acc[4][4];
#pragma unroll
  for (int j = 0; j < 4; ++j) {
    float bv = bcat[nbase + wn + j * 16 + l15];
#pragma unroll
    for (int i = 0; i < 4; ++i) acc[i][j] = (f32x4){bv, bv, bv, bv};
  }

  const int sr = tid >> 2;
  const int skk = (tid & 3) * 8;

  for (int kt = 0; kt < 16; ++kt) {
    const int kb = kt * 32;
#pragma unroll
    for (int pass = 0; pass < 2; ++pass) {
      int rr = sr + pass * 64;
      *(short8*)&As[rr * 40 + skk] = *(const short8*)&A[(long)(mbase + rr) * 512 + kb + skk];
      *(short8*)&Bs[rr * 40 + skk] = *(const short8*)&Bt[(long)(nbase + rr) * 512 + kb + skk];
    }
    __syncthreads();
    short8 af[4], bfr[4];
#pragma unroll
    for (int i = 0; i < 4; ++i)
      af[i] = *(const short8*)&As[(wm + i * 16 + l15) * 40 + q * 8];
#pragma unroll
    for (int j = 0; j < 4; ++j)
      bfr[j] = *(const short8*)&Bs[(wn + j * 16 + l15) * 40 + q * 8];
#pragma unroll
    for (int i = 0; i < 4; ++i)
#pragma unroll
      for (int j = 0; j < 4; ++j)
        acc[i][j] = __builtin_amdgcn_mfma_f32_16x16x32_bf16(af[i], bfr[j], acc[i][j], 0, 0, 0);
    __syncthreads();
  }

#pragma unroll
  for (int i = 0; i < 4; ++i) {
#pragma unroll
    for (int r = 0; r < 4; ++r) {
      int m = mbase + wm + i * 16 + q * 4 + r;
      int b = m >> 10, s = m & 1023;
      long rowoff = ((long)(s * 64 + b)) * 2048;
#pragma unroll
      for (int j = 0; j < 4; ++j) {
        int n = nbase + wn + j * 16 + l15;
        xg[rowoff + n] = f2bf(acc[i][j][r]);
      }
    }
  }
}

// ---------- phase 2: persistent recurrence, 64 WGs, fence-free MALL coherence ----------
// WG j owns h-cols [j*8, j*8+8). All cross-WG traffic (h pairs + epoch flags) uses
// AGENT-scope relaxed atomics => sc0|sc1 => served at the MALL coherence point; no
// buffer_wbl2 / buffer_inv anywhere. __syncthreads' vmcnt(0) drain orders h-store
// completion (ack from MALL) before the flag publish.
__global__ __launch_bounds__(256, 1) void lstm_rec_k(const ushort* __restrict__ xg,
                                                     const ushort* __restrict__ Wht,
                                                     float* __restrict__ out,
                                                     unsigned* hb, unsigned* flags) {
  const int j = blockIdx.x;        // 0..63
  const int tid = threadIdx.x;
  const int wave = tid >> 6, lane = tid & 63;
  const int l15 = lane & 15, q = lane >> 4;

  // B fragments: bfrag[ntile p][ktile]; B[k][n]: n = lane&15, k = kt*32 + q*8 + 0..7
  short8 bfrag[2][16];
#pragma unroll
  for (int p = 0; p < 2; ++p) {
    int nloc = p * 16 + l15;
    int gate = nloc >> 3;
    long ng = gate * 512 + j * 8 + (nloc & 7);
#pragma unroll
    for (int kt = 0; kt < 16; ++kt)
      bfrag[p][kt] = *(const short8*)&Wht[ng * 512 + kt * 32 + q * 8];
  }

  // zero h_0 slice: 64 rows x 4 u32-pairs = 256 slots = 256 threads
  {
    int r = tid >> 2, cp = tid & 3;
    __hip_atomic_store(&hb[r * 256 + j * 4 + cp], 0u, __ATOMIC_RELAXED,
                       __HIP_MEMORY_SCOPE_AGENT);
  }

  float c4[4] = {0.f, 0.f, 0.f, 0.f};
  const int row0 = wave * 16 + q * 4;       // C-layout rows this lane owns
  const int hcol = j * 8 + (lane & 7);
  const bool wr = (lane & 8) == 0;          // gate-dedup writer lanes
  const bool wrp = wr && ((lane & 1) == 0); // pair writer lanes (u32 / float2)
  int gcol[2];
#pragma unroll
  for (int p = 0; p < 2; ++p) {
    int nloc = p * 16 + l15;
    gcol[p] = (nloc >> 3) * 512 + j * 8 + (nloc & 7);
  }
  const int arow = wave * 16 + l15;         // A-fragment row

  // publish h_0, prefetch xg[t=0] under the spin
  __syncthreads();
  if (tid == 0)
    __hip_atomic_store(&flags[j], 1u, __ATOMIC_RELAXED, __HIP_MEMORY_SCOPE_AGENT);
  float xpre[2][4];
#pragma unroll
  for (int p = 0; p < 2; ++p)
#pragma unroll
    for (int r = 0; r < 4; ++r)
      xpre[p][r] = bf2f(xg[(long)(row0 + r) * 2048 + gcol[p]]);
  if (wave == 0) {
    while (__hip_atomic_load(&flags[lane], __ATOMIC_RELAXED,
                             __HIP_MEMORY_SCOPE_AGENT) < 1u) {}
  }
  __syncthreads();

  for (int t = 0; t < 1024; ++t) {
    const unsigned* hrow = hb + (t & 1) * (64 * 256) + arow * 256;

    // A fragments from the MALL-coherent h buffer (dwordx2 sc0 sc1 loads)
    union { unsigned long long u[2]; short8 s8; } afu[16];
#pragma unroll
    for (int kt = 0; kt < 16; ++kt) {
      const unsigned long long* p =
          (const unsigned long long*)(hrow + kt * 16 + q * 4);
      afu[kt].u[0] = __hip_atomic_load(p, __ATOMIC_RELAXED, __HIP_MEMORY_SCOPE_AGENT);
      afu[kt].u[1] = __hip_atomic_load(p + 1, __ATOMIC_RELAXED, __HIP_MEMORY_SCOPE_AGENT);
    }

    f32x4 acc[2];
#pragma unroll
    for (int p = 0; p < 2; ++p)
#pragma unroll
      for (int r = 0; r < 4; ++r)
        acc[p][r] = xpre[p][r];

#pragma unroll
    for (int kt = 0; kt < 16; ++kt) {
      acc[0] = __builtin_amdgcn_mfma_f32_16x16x32_bf16(afu[kt].s8, bfrag[0][kt], acc[0], 0, 0, 0);
      acc[1] = __builtin_amdgcn_mfma_f32_16x16x32_bf16(afu[kt].s8, bfrag[1][kt], acc[1], 0, 0, 0);
    }

    // elementwise: lane (bit3=0) has i (acc0), o (acc1); partner lane^8 has f, g
    const int wt = (t + 1) & 1;
    unsigned* hdst = hb + wt * (64 * 256);
#pragma unroll
    for (int r = 0; r < 4; ++r) {
      float a0 = acc[0][r], a1 = acc[1][r];
      float o0 = __shfl_xor(a0, 8);
      float o1 = __shfl_xor(a1, 8);
      float pi = wr ? a0 : o0;
      float pf = wr ? o0 : a0;
      float po = wr ? a1 : o1;
      float pg = wr ? o1 : a1;
      float ig = sigm(pi), fg = sigm(pf), og = sigm(po), gg = tanh_fast(pg);
      float cc = fg * c4[r] + ig * gg;
      c4[r] = cc;
      float hn = og * tanh_fast(cc);
      float hnp = __shfl_xor(hn, 1);        // partner col's h (odd lane -> even lane)
      int m = row0 + r;
      if (wrp) {
        unsigned pack = (unsigned)f2bf(hn) | ((unsigned)f2bf(hnp) << 16);
        __hip_atomic_store(&hdst[m * 256 + j * 4 + ((lane & 6) >> 1)], pack,
                           __ATOMIC_RELAXED, __HIP_MEMORY_SCOPE_AGENT);
        *(float2*)&out[(long)m * (NS * NH) + (long)t * NH + j * 8 + (lane & 6)] =
            make_float2(hn, hnp);
      }
      if (t == 1023 && wr) {
        out[OUT_HF + m * 512 + hcol] = hn;
        out[OUT_CF + m * 512 + hcol] = cc;
      }
    }

    if (t < 1023) {
      __syncthreads();                      // drains vmcnt(0): h stores ack'd at MALL
      if (tid == 0)
        __hip_atomic_store(&flags[j], (unsigned)(t + 2), __ATOMIC_RELAXED,
                           __HIP_MEMORY_SCOPE_AGENT);
      // prefetch next step's xg under the spin (read-only, L1/L2-cacheable)
      long xb2 = ((long)(t + 1) * 64) * 2048;
#pragma unroll
      for (int p = 0; p < 2; ++p)
#pragma unroll
        for (int r = 0; r < 4; ++r)
          xpre[p][r] = bf2f(xg[xb2 + (long)(row0 + r) * 2048 + gcol[p]]);
      if (wave == 0) {
        unsigned tgt = (unsigned)(t + 2);
        while (__hip_atomic_load(&flags[lane], __ATOMIC_RELAXED,
                                 __HIP_MEMORY_SCOPE_AGENT) < tgt) {}
      }
      __syncthreads();
    }
  }
}

extern "C" void kernel_launch(void* const* d_in, const int* in_sizes, int n_in,
                              void* d_out, int out_size, void* d_ws, size_t ws_size,
                              hipStream_t stream) {
  const float* inputs = (const float*)d_in[0];
  const float* Wxi = (const float*)d_in[1];
  const float* Whi = (const float*)d_in[2];
  const float* bi  = (const float*)d_in[3];
  const float* Wxf = (const float*)d_in[4];
  const float* Whf = (const float*)d_in[5];
  const float* bff = (const float*)d_in[6];
  const float* Wxo = (const float*)d_in[7];
  const float* Who = (const float*)d_in[8];
  const float* bo  = (const float*)d_in[9];
  const float* Wxc = (const float*)d_in[10];
  const float* Whc = (const float*)d_in[11];
  const float* bc  = (const float*)d_in[12];

  char* ws = (char*)d_ws;
  ushort*  Abf  = (ushort*)(ws + OFF_A);
  ushort*  xgp  = (ushort*)(ws + OFF_XG);
  ushort*  Wxt  = (ushort*)(ws + OFF_WXT);
  ushort*  Whtp = (ushort*)(ws + OFF_WHT);
  float*   bcat = (float*)(ws + OFF_BC);
  unsigned* hb  = (unsigned*)(ws + OFF_HB);
  unsigned* flags = (unsigned*)(ws + OFF_BAR);

  hipMemsetAsync(flags, 0, 64 * sizeof(unsigned), stream);

  cvt_in_k<<<16384, 256, 0, stream>>>(inputs, Abf);
  prep_w_k<<<4096, 256, 0, stream>>>(Wxi, Whi, bi, Wxf, Whf, bff,
                                     Wxo, Who, bo, Wxc, Whc, bc,
                                     Wxt, Whtp, bcat);
  dim3 g1(M1 / 128, NG / 128);                                      // 512 x 16
  gemm_x_k<<<g1, 256, 0, stream>>>(Abf, Wxt, bcat, xgp);
  lstm_rec_k<<<64, 256, 0, stream>>>(xgp, Whtp, (float*)d_out, hb, flags);
}

// Round 3
// 6606.155 us; speedup vs baseline: 1.3862x; 1.0679x over previous
//
#include <hip/hip_runtime.h>
#include <hip/hip_bf16.h>

typedef __attribute__((ext_vector_type(8))) short short8;
typedef __attribute__((ext_vector_type(4))) float f32x4;

// Problem dims
#define NB 64      // batch
#define NS 1024    // seq
#define ND 512     // input dim
#define NH 512     // hidden
#define NG 2048    // 4*NH gate columns
#define M1 65536   // NB*NS rows of the input-projection GEMM

// ws layout (bytes)
#define OFF_A    0L                      // A bf16 [65536][512]           64 MB
#define OFF_XG   67108864L               // xg bf16 [1024][64][2048]     256 MB
#define OFF_WXT  335544320L              // Wxt bf16 [2048][512]           2 MB
#define OFF_WHT  337641472L              // Wht bf16 [2048][512]           2 MB
#define OFF_BC   339738624L              // bcat f32 [2048]                8 KB
#define OFF_HB   339746816L              // hb u32 [2][64][256]          128 KB (bf16 pairs)
#define OFF_BAR  339877888L              // flags u32[64]

#define OUT_HF   33554432L               // d_out offset of h_final
#define OUT_CF   33587200L               // d_out offset of c_final

static __device__ __forceinline__ ushort f2bf(float x) {
  union { float f; unsigned u; } v; v.f = x;
  unsigned r = (v.u + 0x7FFFu + ((v.u >> 16) & 1u)) >> 16;
  return (ushort)r;
}
static __device__ __forceinline__ float bf2f(ushort x) {
  union { unsigned u; float f; } v; v.u = ((unsigned)x) << 16; return v.f;
}
static __device__ __forceinline__ float sigm(float x) {
  return 1.0f / (1.0f + __expf(-x));
}
static __device__ __forceinline__ float tanh_fast(float x) {
  return 2.0f / (1.0f + __expf(-2.0f * x)) - 1.0f;
}

// ---------- phase 0a: fp32 -> bf16 convert of inputs ----------
__global__ __launch_bounds__(256) void cvt_in_k(const float* __restrict__ in,
                                                ushort* __restrict__ out) {
  long i = ((long)blockIdx.x * 256 + threadIdx.x) * 8;
  const float4* p = (const float4*)(in + i);
  float4 a = p[0], b = p[1];
  short8 o;
  o[0] = (short)f2bf(a.x); o[1] = (short)f2bf(a.y);
  o[2] = (short)f2bf(a.z); o[3] = (short)f2bf(a.w);
  o[4] = (short)f2bf(b.x); o[5] = (short)f2bf(b.y);
  o[6] = (short)f2bf(b.z); o[7] = (short)f2bf(b.w);
  *(short8*)(out + i) = o;
}

// ---------- phase 0b: transpose+convert weights, pack biases ----------
__global__ __launch_bounds__(256) void prep_w_k(
    const float* __restrict__ Wxi, const float* __restrict__ Whi, const float* __restrict__ bi,
    const float* __restrict__ Wxf, const float* __restrict__ Whf, const float* __restrict__ bff,
    const float* __restrict__ Wxo, const float* __restrict__ Who, const float* __restrict__ bo,
    const float* __restrict__ Wxc, const float* __restrict__ Whc, const float* __restrict__ bc,
    ushort* __restrict__ Wxt, ushort* __restrict__ Wht, float* __restrict__ bcat) {
  int t = blockIdx.x * 256 + threadIdx.x;   // 0 .. 2048*512-1
  int n = t >> 9, k = t & 511;
  int g = n >> 9, col = n & 511;
  const float* wx = (g == 0) ? Wxi : (g == 1) ? Wxf : (g == 2) ? Wxo : Wxc;
  const float* wh = (g == 0) ? Whi : (g == 1) ? Whf : (g == 2) ? Who : Whc;
  Wxt[t] = f2bf(wx[k * 512 + col]);
  Wht[t] = f2bf(wh[k * 512 + col]);
  if (t < 2048) {
    int g2 = t >> 9;
    const float* bp = (g2 == 0) ? bi : (g2 == 1) ? bff : (g2 == 2) ? bo : bc;
    bcat[t] = bp[t & 511];
  }
}

// ---------- phase 1: xg = A @ Wxt^T + b  (bf16 MFMA, 128x128 tiles, BK=32) ----------
__global__ __launch_bounds__(256) void gemm_x_k(const ushort* __restrict__ A,
                                                const ushort* __restrict__ Bt,
                                                const float* __restrict__ bcat,
                                                ushort* __restrict__ xg) {
  __shared__ ushort As[128 * 40];
  __shared__ ushort Bs[128 * 40];
  const int mbase = blockIdx.x * 128;
  const int nbase = blockIdx.y * 128;
  const int tid = threadIdx.x;
  const int lane = tid & 63, wave = tid >> 6;
  const int l15 = lane & 15, q = lane >> 4;
  const int wm = (wave & 1) * 64, wn = (wave >> 1) * 64;

  f32x4 acc[4][4];
#pragma unroll
  for (int j = 0; j < 4; ++j) {
    float bv = bcat[nbase + wn + j * 16 + l15];
#pragma unroll
    for (int i = 0; i < 4; ++i) acc[i][j] = (f32x4){bv, bv, bv, bv};
  }

  const int sr = tid >> 2;
  const int skk = (tid & 3) * 8;

  for (int kt = 0; kt < 16; ++kt) {
    const int kb = kt * 32;
#pragma unroll
    for (int pass = 0; pass < 2; ++pass) {
      int rr = sr + pass * 64;
      *(short8*)&As[rr * 40 + skk] = *(const short8*)&A[(long)(mbase + rr) * 512 + kb + skk];
      *(short8*)&Bs[rr * 40 + skk] = *(const short8*)&Bt[(long)(nbase + rr) * 512 + kb + skk];
    }
    __syncthreads();
    short8 af[4], bfr[4];
#pragma unroll
    for (int i = 0; i < 4; ++i)
      af[i] = *(const short8*)&As[(wm + i * 16 + l15) * 40 + q * 8];
#pragma unroll
    for (int j = 0; j < 4; ++j)
      bfr[j] = *(const short8*)&Bs[(wn + j * 16 + l15) * 40 + q * 8];
#pragma unroll
    for (int i = 0; i < 4; ++i)
#pragma unroll
      for (int j = 0; j < 4; ++j)
        acc[i][j] = __builtin_amdgcn_mfma_f32_16x16x32_bf16(af[i], bfr[j], acc[i][j], 0, 0, 0);
    __syncthreads();
  }

#pragma unroll
  for (int i = 0; i < 4; ++i) {
#pragma unroll
    for (int r = 0; r < 4; ++r) {
      int m = mbase + wm + i * 16 + q * 4 + r;
      int b = m >> 10, s = m & 1023;
      long rowoff = ((long)(s * 64 + b)) * 2048;
#pragma unroll
      for (int j = 0; j < 4; ++j) {
        int n = nbase + wn + j * 16 + l15;
        xg[rowoff + n] = f2bf(acc[i][j][r]);
      }
    }
  }
}

// ---------- phase 2: persistent recurrence, 64 WGs, fence-free MALL coherence ----------
// WG j owns h-cols [j*8, j*8+8). Cross-WG traffic (h pairs + epoch flags) uses
// AGENT-scope relaxed atomics (sc0|sc1 -> MALL coherence point); no cache
// maintenance ops. Step tail order: h stores (sc1) -> __syncthreads (vmcnt
// drain = h ack'd at MALL) -> flag publish -> out stores (retire during next
// step, off critical path) -> xg prefetch -> spin.
__global__ __launch_bounds__(256, 1) void lstm_rec_k(const ushort* __restrict__ xg,
                                                     const ushort* __restrict__ Wht,
                                                     float* __restrict__ out,
                                                     unsigned* hb, unsigned* flags) {
  const int j = blockIdx.x;        // 0..63
  const int tid = threadIdx.x;
  const int wave = tid >> 6, lane = tid & 63;
  const int l15 = lane & 15, q = lane >> 4;

  // B fragments: bfrag[ntile p][ktile]; B[k][n]: n = lane&15, k = kt*32 + q*8 + 0..7
  short8 bfrag[2][16];
#pragma unroll
  for (int p = 0; p < 2; ++p) {
    int nloc = p * 16 + l15;
    int gate = nloc >> 3;
    long ng = gate * 512 + j * 8 + (nloc & 7);
#pragma unroll
    for (int kt = 0; kt < 16; ++kt)
      bfrag[p][kt] = *(const short8*)&Wht[ng * 512 + kt * 32 + q * 8];
  }
  // Pin the weight slice in VGPRs: the asm tie makes rematerialization of the
  // loads into the time loop illegal. 128 VGPRs held for the whole kernel.
#pragma unroll
  for (int p = 0; p < 2; ++p)
#pragma unroll
    for (int kt = 0; kt < 16; ++kt)
      asm volatile("" : "+v"(bfrag[p][kt]));

  // zero h_0 slice: 64 rows x 4 u32-pairs = 256 slots = 256 threads
  {
    int r = tid >> 2, cp = tid & 3;
    __hip_atomic_store(&hb[r * 256 + j * 4 + cp], 0u, __ATOMIC_RELAXED,
                       __HIP_MEMORY_SCOPE_AGENT);
  }

  float c4[4] = {0.f, 0.f, 0.f, 0.f};
  float hsave[4] = {0.f, 0.f, 0.f, 0.f};
  float hpsave[4] = {0.f, 0.f, 0.f, 0.f};
  const int row0 = wave * 16 + q * 4;       // C-layout rows this lane owns
  const int hcol = j * 8 + (lane & 7);
  const bool wr = (lane & 8) == 0;          // gate-dedup writer lanes
  const bool wrp = wr && ((lane & 1) == 0); // pair writer lanes (u32 / float2)
  int gcol[2];
#pragma unroll
  for (int p = 0; p < 2; ++p) {
    int nloc = p * 16 + l15;
    gcol[p] = (nloc >> 3) * 512 + j * 8 + (nloc & 7);
  }
  const int arow = wave * 16 + l15;         // A-fragment row

  // publish h_0, prefetch xg[t=0] under the spin
  __syncthreads();
  if (tid == 0)
    __hip_atomic_store(&flags[j], 1u, __ATOMIC_RELAXED, __HIP_MEMORY_SCOPE_AGENT);
  float xpre[2][4];
#pragma unroll
  for (int p = 0; p < 2; ++p)
#pragma unroll
    for (int r = 0; r < 4; ++r)
      xpre[p][r] = bf2f(xg[(long)(row0 + r) * 2048 + gcol[p]]);
  if (wave == 0) {
    while (__hip_atomic_load(&flags[lane], __ATOMIC_RELAXED,
                             __HIP_MEMORY_SCOPE_AGENT) < 1u) {}
  }
  __syncthreads();

  for (int t = 0; t < 1024; ++t) {
    const unsigned* hrow = hb + (t & 1) * (64 * 256) + arow * 256;

    // A fragments from the MALL-coherent h buffer (dwordx2 sc0 sc1 loads)
    union { unsigned long long u[2]; short8 s8; } afu[16];
#pragma unroll
    for (int kt = 0; kt < 16; ++kt) {
      const unsigned long long* p =
          (const unsigned long long*)(hrow + kt * 16 + q * 4);
      afu[kt].u[0] = __hip_atomic_load(p, __ATOMIC_RELAXED, __HIP_MEMORY_SCOPE_AGENT);
      afu[kt].u[1] = __hip_atomic_load(p + 1, __ATOMIC_RELAXED, __HIP_MEMORY_SCOPE_AGENT);
    }

    f32x4 acc[2];
#pragma unroll
    for (int p = 0; p < 2; ++p)
#pragma unroll
      for (int r = 0; r < 4; ++r)
        acc[p][r] = xpre[p][r];

#pragma unroll
    for (int kt = 0; kt < 16; ++kt) {
      acc[0] = __builtin_amdgcn_mfma_f32_16x16x32_bf16(afu[kt].s8, bfrag[0][kt], acc[0], 0, 0, 0);
      acc[1] = __builtin_amdgcn_mfma_f32_16x16x32_bf16(afu[kt].s8, bfrag[1][kt], acc[1], 0, 0, 0);
    }

    // elementwise: lane (bit3=0) has i (acc0), o (acc1); partner lane^8 has f, g.
    // h stores issue immediately per-r (earliest sc1 issue); out stores deferred.
    const int wt = (t + 1) & 1;
    unsigned* hdst = hb + wt * (64 * 256);
#pragma unroll
    for (int r = 0; r < 4; ++r) {
      float a0 = acc[0][r], a1 = acc[1][r];
      float o0 = __shfl_xor(a0, 8);
      float o1 = __shfl_xor(a1, 8);
      float pi = wr ? a0 : o0;
      float pf = wr ? o0 : a0;
      float po = wr ? a1 : o1;
      float pg = wr ? o1 : a1;
      float ig = sigm(pi), fg = sigm(pf), og = sigm(po), gg = tanh_fast(pg);
      float cc = fg * c4[r] + ig * gg;
      c4[r] = cc;
      float hn = og * tanh_fast(cc);
      float hnp = __shfl_xor(hn, 1);        // partner col's h (odd lane -> even lane)
      hsave[r] = hn;
      hpsave[r] = hnp;
      if (wrp) {
        unsigned pack = (unsigned)f2bf(hn) | ((unsigned)f2bf(hnp) << 16);
        __hip_atomic_store(&hdst[(row0 + r) * 256 + j * 4 + ((lane & 6) >> 1)], pack,
                           __ATOMIC_RELAXED, __HIP_MEMORY_SCOPE_AGENT);
      }
    }

    if (t < 1023) {
      __syncthreads();                      // drains vmcnt(0): h stores ack'd at MALL
      if (tid == 0)
        __hip_atomic_store(&flags[j], (unsigned)(t + 2), __ATOMIC_RELAXED,
                           __HIP_MEMORY_SCOPE_AGENT);
    }

    // out stores AFTER the flag publish: they have a full step to retire before
    // the next iteration's vmcnt drain — off the critical path.
    if (wrp) {
#pragma unroll
      for (int r = 0; r < 4; ++r)
        *(float2*)&out[(long)(row0 + r) * (NS * NH) + (long)t * NH + j * 8 + (lane & 6)] =
            make_float2(hsave[r], hpsave[r]);
    }

    if (t < 1023) {
      // prefetch next step's xg under the spin (read-only, cached)
      long xb2 = ((long)(t + 1) * 64) * 2048;
#pragma unroll
      for (int p = 0; p < 2; ++p)
#pragma unroll
        for (int r = 0; r < 4; ++r)
          xpre[p][r] = bf2f(xg[xb2 + (long)(row0 + r) * 2048 + gcol[p]]);
      if (wave == 0) {
        unsigned tgt = (unsigned)(t + 2);
        while (__hip_atomic_load(&flags[lane], __ATOMIC_RELAXED,
                                 __HIP_MEMORY_SCOPE_AGENT) < tgt) {}
      }
      __syncthreads();
    }
  }

  // final h / c state (t = 1023 values still in registers)
  if (wr) {
#pragma unroll
    for (int r = 0; r < 4; ++r) {
      int m = row0 + r;
      out[OUT_HF + m * 512 + hcol] = hsave[r];
      out[OUT_CF + m * 512 + hcol] = c4[r];
    }
  }
}

extern "C" void kernel_launch(void* const* d_in, const int* in_sizes, int n_in,
                              void* d_out, int out_size, void* d_ws, size_t ws_size,
                              hipStream_t stream) {
  const float* inputs = (const float*)d_in[0];
  const float* Wxi = (const float*)d_in[1];
  const float* Whi = (const float*)d_in[2];
  const float* bi  = (const float*)d_in[3];
  const float* Wxf = (const float*)d_in[4];
  const float* Whf = (const float*)d_in[5];
  const float* bff = (const float*)d_in[6];
  const float* Wxo = (const float*)d_in[7];
  const float* Who = (const float*)d_in[8];
  const float* bo  = (const float*)d_in[9];
  const float* Wxc = (const float*)d_in[10];
  const float* Whc = (const float*)d_in[11];
  const float* bc  = (const float*)d_in[12];

  char* ws = (char*)d_ws;
  ushort*  Abf  = (ushort*)(ws + OFF_A);
  ushort*  xgp  = (ushort*)(ws + OFF_XG);
  ushort*  Wxt  = (ushort*)(ws + OFF_WXT);
  ushort*  Whtp = (ushort*)(ws + OFF_WHT);
  float*   bcat = (float*)(ws + OFF_BC);
  unsigned* hb  = (unsigned*)(ws + OFF_HB);
  unsigned* flags = (unsigned*)(ws + OFF_BAR);

  hipMemsetAsync(flags, 0, 64 * sizeof(unsigned), stream);

  cvt_in_k<<<16384, 256, 0, stream>>>(inputs, Abf);
  prep_w_k<<<4096, 256, 0, stream>>>(Wxi, Whi, bi, Wxf, Whf, bff,
                                     Wxo, Who, bo, Wxc, Whc, bc,
                                     Wxt, Whtp, bcat);
  dim3 g1(M1 / 128, NG / 128);                                      // 512 x 16
  gemm_x_k<<<g1, 256, 0, stream>>>(Abf, Wxt, bcat, xgp);
  lstm_rec_k<<<64, 256, 0, stream>>>(xgp, Whtp, (float*)d_out, hb, flags);
}